// Round 7
// baseline (320.696 us; speedup 1.0000x reference)
//
#include <hip/hip_runtime.h>
#include <hip/hip_bf16.h>
#include <cstdint>

typedef __hip_bfloat16 bf16;
typedef __attribute__((ext_vector_type(8))) short bf16x8;
typedef __attribute__((ext_vector_type(4))) float f32x4;
typedef __attribute__((ext_vector_type(4))) int i32x4;

#define T_SEQ 2048
#define DMODEL 1024
#define NHEAD 16
#define DHEAD 64
#define MROWS 4096

typedef const __attribute__((address_space(1))) void* gas_ptr;
typedef __attribute__((address_space(3))) void* las_ptr;

static __device__ __forceinline__ f32x4 mfma16(bf16x8 a, bf16x8 b, f32x4 c) {
  return __builtin_amdgcn_mfma_f32_16x16x32_bf16(a, b, c, 0, 0, 0);
}
static __device__ __forceinline__ void gload_lds16(const void* g, void* l) {
  __builtin_amdgcn_global_load_lds((gas_ptr)g, (las_ptr)l, 16, 0, 0);
}
static __device__ __forceinline__ float b2f(unsigned short u) {
  union { unsigned int i; float f; } x; x.i = ((unsigned int)u) << 16; return x.f;
}
static __device__ __forceinline__ unsigned short f2bu(float f) {
  __hip_bfloat16 h = __float2bfloat16(f);
  unsigned short u; __builtin_memcpy(&u, &h, 2); return u;
}

// ---------------- weight fp32 -> bf16 ----------------
__global__ void f2b_k(const float* __restrict__ in, bf16* __restrict__ out, int n) {
  int idx = (blockIdx.x * blockDim.x + threadIdx.x) * 4;
  if (idx < n) {
    float4 v = *(const float4*)(in + idx);
    out[idx]     = __float2bfloat16(v.x);
    out[idx + 1] = __float2bfloat16(v.y);
    out[idx + 2] = __float2bfloat16(v.z);
    out[idx + 3] = __float2bfloat16(v.w);
  }
}

// ---------------- RMSNorm: fp32 in -> bf16 out ----------------
__global__ __launch_bounds__(256) void rms_k(const float* __restrict__ x,
                                             const float* __restrict__ w,
                                             bf16* __restrict__ out) {
  const int row = blockIdx.x;
  const int tid = threadIdx.x;
  const float4 v = ((const float4*)(x + (size_t)row * DMODEL))[tid];
  float ss = v.x * v.x + v.y * v.y + v.z * v.z + v.w * v.w;
#pragma unroll
  for (int off = 32; off; off >>= 1) ss += __shfl_xor(ss, off);
  __shared__ float red[4];
  if ((tid & 63) == 0) red[tid >> 6] = ss;
  __syncthreads();
  const float tot = red[0] + red[1] + red[2] + red[3];
  const float rinv = rsqrtf(tot * (1.f / DMODEL) + 1e-6f);
  const float4 wv = ((const float4*)w)[tid];
  bf16* o = out + (size_t)row * DMODEL + tid * 4;
  o[0] = __float2bfloat16(v.x * rinv * wv.x);
  o[1] = __float2bfloat16(v.y * rinv * wv.y);
  o[2] = __float2bfloat16(v.z * rinv * wv.z);
  o[3] = __float2bfloat16(v.w * rinv * wv.w);
}

// ---------------- GEMM: C = A(M,K) x Bw(N,K)^T, bf16 in, fp32 accum ----------------
// m97 structure: 128x128 tile, BK=32, 4 waves, global_load_lds width=16.
// EPI: 0 = bf16 store to o0 (ld=N)
//      1 = qkv scatter: Q,K as (B,H,T,64) to o0/o1; V TRANSPOSED as (B,H,64,T) to o2
//      2 = fp32 store o0 = res + C (ld=N)
//      3 = split-N: cols [0,N/2) -> o0, [N/2,N) -> o1, each compact ld=N/2 bf16
template <int K, int EPI>
__global__ __launch_bounds__(256) void gemm_bt(const bf16* __restrict__ A,
                                               const bf16* __restrict__ Bw, int N,
                                               void* __restrict__ o0, void* __restrict__ o1,
                                               void* __restrict__ o2,
                                               const float* __restrict__ res) {
  __shared__ bf16 As[128 * 32];
  __shared__ bf16 Bs[128 * 32];
  const int bn0 = blockIdx.x * 128;
  const int bm0 = blockIdx.y * 128;
  const int tid = threadIdx.x;
  const int wave = tid >> 6, lane = tid & 63;
  const int wr = wave >> 1, wc = wave & 1;
  const int fr = lane & 15, g8 = (lane >> 4) * 8, r4 = (lane >> 4) * 4;
  const int srow = lane >> 2;
  const int scol = (lane & 3) * 8;

  const f32x4 fzero = {0.f, 0.f, 0.f, 0.f};
  f32x4 acc[4][4];
#pragma unroll
  for (int i = 0; i < 4; i++)
#pragma unroll
    for (int j = 0; j < 4; j++) acc[i][j] = fzero;

  const bf16* gA0 = A + (size_t)(bm0 + wave * 16 + srow) * K + scol;
  const bf16* gA1 = A + (size_t)(bm0 + (wave + 4) * 16 + srow) * K + scol;
  const bf16* gB0 = Bw + (size_t)(bn0 + wave * 16 + srow) * K + scol;
  const bf16* gB1 = Bw + (size_t)(bn0 + (wave + 4) * 16 + srow) * K + scol;

  for (int k0 = 0; k0 < K; k0 += 32) {
    gload_lds16(gA0 + k0, &As[wave * 512]);
    gload_lds16(gA1 + k0, &As[(wave + 4) * 512]);
    gload_lds16(gB0 + k0, &Bs[wave * 512]);
    gload_lds16(gB1 + k0, &Bs[(wave + 4) * 512]);
    __syncthreads();
    bf16x8 af[4], bfr[4];
#pragma unroll
    for (int mr = 0; mr < 4; mr++)
      af[mr] = *(const bf16x8*)&As[(wr * 64 + mr * 16 + fr) * 32 + g8];
#pragma unroll
    for (int nr = 0; nr < 4; nr++)
      bfr[nr] = *(const bf16x8*)&Bs[(wc * 64 + nr * 16 + fr) * 32 + g8];
#pragma unroll
    for (int mr = 0; mr < 4; mr++)
#pragma unroll
      for (int nr = 0; nr < 4; nr++)
        acc[mr][nr] = mfma16(af[mr], bfr[nr], acc[mr][nr]);
    __syncthreads();
  }

#pragma unroll
  for (int mr = 0; mr < 4; mr++) {
#pragma unroll
    for (int nr = 0; nr < 4; nr++) {
#pragma unroll
      for (int r = 0; r < 4; r++) {
        const int row = bm0 + wr * 64 + mr * 16 + r4 + r;
        const int col = bn0 + wc * 64 + nr * 16 + fr;
        const float vsum = acc[mr][nr][r];
        if (EPI == 0) {
          ((bf16*)o0)[(size_t)row * N + col] = __float2bfloat16(vsum);
        } else if (EPI == 1) {
          const int sel = col >> 10;
          const int n = col & 1023;
          const int h = n >> 6, d = n & 63;
          const int b = row >> 11, t = row & 2047;
          if (sel == 2) {
            // V transposed: (B,H,D,T)
            ((bf16*)o2)[(((size_t)(b * NHEAD + h)) * DHEAD + d) * T_SEQ + t] =
                __float2bfloat16(vsum);
          } else {
            bf16* dst = (sel == 0) ? (bf16*)o0 : (bf16*)o1;
            dst[(((size_t)(b * NHEAD + h)) * T_SEQ + t) * DHEAD + d] = __float2bfloat16(vsum);
          }
        } else if (EPI == 2) {
          ((float*)o0)[(size_t)row * N + col] = res[(size_t)row * N + col] + vsum;
        } else {
          const int half = N >> 1;
          bf16* dst = (col < half) ? (bf16*)o0 : (bf16*)o1;
          const int c = (col < half) ? col : col - half;
          dst[(size_t)row * half + c] = __float2bfloat16(vsum);
        }
      }
    }
  }
}

// ---------------- causal flash attention, 2-way key-split ----------------
// Unnormalized softmax (no running max) => partials are ADDITIVE over keys.
// 4096 balanced wave-tasks: 1024 blocks x 4 waves.
//   c = blk&7 (XCD), j = blk>>3; bh = c*4 + (j>>5)  (XCD-local heads, r5-verified)
//   tt = (j&31)*4 + wave; pp = tt>>1 (pair), hh = tt&1 (key-half parity)
//   wave handles groups {pp, 127-pp}, processing 32-key blocks bi with
//   (bi&1)==hh  -> every wave ~33 iterations (flat balance), 2x wave count.
// Body identical to round-6-verified: swapped QK^T (S^T), register-shuffle P^T
// rebuild, PV = mfma(V^T,P^T) = O^T. No LDS, no fences.
// Wave stores RAW partial O^T (bf16) + partial lsum (f32) to slot hh;
// comb_k sums the 2 slots and normalizes into Y.
__global__ __launch_bounds__(256) void attn_k(const bf16* __restrict__ qb,
                                              const bf16* __restrict__ kb,
                                              const bf16* __restrict__ vt,
                                              unsigned short* __restrict__ pO,
                                              float* __restrict__ pL) {
  const int wave = threadIdx.x >> 6, lane = threadIdx.x & 63;
  const int c = blockIdx.x & 7;
  const int j = blockIdx.x >> 3;
  const int bh = c * 4 + (j >> 5);
  const int tt = (j & 31) * 4 + wave;
  const int pp = tt >> 1;
  const int hh = tt & 1;
  const int fr = lane & 15, g8 = (lane >> 4) * 8, r4 = (lane >> 4) * 4;
  const int d2 = lane >> 4;                  // P^T dest k-block index
  const int src1 = fr + ((d2 & 1) << 5);     // qg0 / qg2 partner lane
  const int src2 = src1 + 16;                // qg1 / qg3 partner lane
  const bool hB = d2 >= 2;                   // low/high half of k-tile

  const bf16* qp = qb + (size_t)bh * T_SEQ * DHEAD;
  const bf16* kp = kb + (size_t)bh * T_SEQ * DHEAD;
  const bf16* vp = vt + (size_t)bh * DHEAD * T_SEQ;

  const f32x4 fzero = {0.f, 0.f, 0.f, 0.f};

#pragma unroll 1
  for (int ph = 0; ph < 2; ph++) {
    const int g = ph ? (127 - pp) : pp;
    const int q0 = g * 16;
    const int nb = (g >> 1) + 1;     // # 32-key blocks in this group's range
    const int qrow = q0 + fr;

    const bf16x8 qf0 = *(const bf16x8*)(qp + (size_t)(q0 + fr) * DHEAD + g8);
    const bf16x8 qf1 = *(const bf16x8*)(qp + (size_t)(q0 + fr) * DHEAD + 32 + g8);

    f32x4 acc[4];
    float lpart = 0.f;
#pragma unroll
    for (int nf = 0; nf < 4; nf++) acc[nf] = fzero;

    for (int bi = hh; bi < nb; bi += 2) {
      const int kt = bi * 32;
      const bf16x8 kf0a = *(const bf16x8*)(kp + (size_t)(kt + fr) * DHEAD + g8);
      const bf16x8 kf0b = *(const bf16x8*)(kp + (size_t)(kt + fr) * DHEAD + 32 + g8);
      const bf16x8 kf1a = *(const bf16x8*)(kp + (size_t)(kt + 16 + fr) * DHEAD + g8);
      const bf16x8 kf1b = *(const bf16x8*)(kp + (size_t)(kt + 16 + fr) * DHEAD + 32 + g8);
      bf16x8 vf[4];
#pragma unroll
      for (int nf = 0; nf < 4; nf++)
        vf[nf] = *(const bf16x8*)(vp + (size_t)(nf * 16 + fr) * T_SEQ + kt + g8);

      // swapped QK^T: S^T[k][q]; lane: q = fr, k_local = r4 + r (+16 for s1)
      f32x4 s0 = mfma16(kf0a, qf0, fzero);
      s0 = mfma16(kf0b, qf1, s0);
      f32x4 s1 = mfma16(kf1a, qf0, fzero);
      s1 = mfma16(kf1b, qf1, s1);

      float x0[4], x1[4];
#pragma unroll
      for (int r = 0; r < 4; r++) {
        const int k0 = kt + r4 + r;
        const int k1 = k0 + 16;
        x0[r] = (k0 <= qrow) ? __expf(fminf(s0[r] * 0.125f, 30.f)) : 0.f;
        x1[r] = (k1 <= qrow) ? __expf(fminf(s1[r] * 0.125f, 30.f)) : 0.f;
        lpart += x0[r] + x1[r];
      }

      // pack P^T values (bf16 pairs along k)
      const int A01 = (int)((unsigned)f2bu(x0[0]) | ((unsigned)f2bu(x0[1]) << 16));
      const int A23 = (int)((unsigned)f2bu(x0[2]) | ((unsigned)f2bu(x0[3]) << 16));
      const int B01 = (int)((unsigned)f2bu(x1[0]) | ((unsigned)f2bu(x1[1]) << 16));
      const int B23 = (int)((unsigned)f2bu(x1[2]) | ((unsigned)f2bu(x1[3]) << 16));

      // rebuild B-frag P^T: dest lane (fr, d2) needs k = 8*d2 .. 8*d2+7
      const int t0a = __shfl(A01, src1), t0b = __shfl(B01, src1);
      const int t1a = __shfl(A23, src1), t1b = __shfl(B23, src1);
      const int t2a = __shfl(A01, src2), t2b = __shfl(B01, src2);
      const int t3a = __shfl(A23, src2), t3b = __shfl(B23, src2);
      i32x4 pw;
      pw[0] = hB ? t0b : t0a;
      pw[1] = hB ? t1b : t1a;
      pw[2] = hB ? t2b : t2a;
      pw[3] = hB ? t3b : t3a;
      const bf16x8 pb = __builtin_bit_cast(bf16x8, pw);

      // PV: O^T partial = V^T * P^T
#pragma unroll
      for (int nf = 0; nf < 4; nf++) acc[nf] = mfma16(vf[nf], pb, acc[nf]);
    }

    // partial lsum for row q=fr: combine the 4 lanes holding its k-subsets
    lpart += __shfl_xor(lpart, 16);
    lpart += __shfl_xor(lpart, 32);

    // store RAW partials to slot hh (every slot written every call)
    const int t = q0 + fr;
    unsigned short* po =
        pO + ((size_t)(hh * 32 + bh) * T_SEQ + t) * DHEAD;
#pragma unroll
    for (int nf = 0; nf < 4; nf++) {
      ushort4 ov;
      ov.x = f2bu(acc[nf][0]);
      ov.y = f2bu(acc[nf][1]);
      ov.z = f2bu(acc[nf][2]);
      ov.w = f2bu(acc[nf][3]);
      *(ushort4*)(po + nf * 16 + r4) = ov;
    }
    if (lane < 16) pL[(size_t)(hh * 32 + bh) * T_SEQ + q0 + lane] = lpart;
  }
}

// ---------------- combine partials + normalize -> Y (B,T,H,64) bf16 ----------
__global__ __launch_bounds__(256) void comb_k(const unsigned short* __restrict__ pO,
                                              const float* __restrict__ pL,
                                              bf16* __restrict__ y) {
  const int idx = blockIdx.x * 256 + threadIdx.x;  // 16 threads per row
  const int row = idx >> 4;                        // bh*2048 + t
  const int d0 = (idx & 15) * 4;
  const int bh = row >> 11, t = row & 2047;
  const int b = bh >> 4, h = bh & 15;
  const float inv = 1.f / (pL[row] + pL[(NHEAD * 2) * T_SEQ + row]);
  const ushort4 a = *(const ushort4*)(pO + (size_t)row * DHEAD + d0);
  const ushort4 bq =
      *(const ushort4*)(pO + (size_t)32 * T_SEQ * DHEAD + (size_t)row * DHEAD + d0);
  ushort4 ov;
  ov.x = f2bu((b2f(a.x) + b2f(bq.x)) * inv);
  ov.y = f2bu((b2f(a.y) + b2f(bq.y)) * inv);
  ov.z = f2bu((b2f(a.z) + b2f(bq.z)) * inv);
  ov.w = f2bu((b2f(a.w) + b2f(bq.w)) * inv);
  *(ushort4*)((unsigned short*)y + (((size_t)(b * T_SEQ + t)) * NHEAD + h) * DHEAD + d0) = ov;
}

// ---------------- gu = silu(g) * u (bf16) ----------------
__global__ void silumul_k(const bf16* __restrict__ g, const bf16* __restrict__ u,
                          bf16* __restrict__ o, int n) {
  const int idx = (blockIdx.x * blockDim.x + threadIdx.x) * 4;
  if (idx < n) {
    const ushort4 gv = *(const ushort4*)((const unsigned short*)g + idx);
    const ushort4 uv = *(const ushort4*)((const unsigned short*)u + idx);
    ushort4 ov;
    float a, s;
    a = b2f(gv.x); s = a / (1.f + __expf(-a)); ov.x = f2bu(s * b2f(uv.x));
    a = b2f(gv.y); s = a / (1.f + __expf(-a)); ov.y = f2bu(s * b2f(uv.y));
    a = b2f(gv.z); s = a / (1.f + __expf(-a)); ov.z = f2bu(s * b2f(uv.z));
    a = b2f(gv.w); s = a / (1.f + __expf(-a)); ov.w = f2bu(s * b2f(uv.w));
    *(ushort4*)((unsigned short*)o + idx) = ov;
  }
}

// ---------------- launch ----------------
extern "C" void kernel_launch(void* const* d_in, const int* in_sizes, int n_in,
                              void* d_out, int out_size, void* d_ws, size_t ws_size,
                              hipStream_t stream) {
  const float* x     = (const float*)d_in[0];
  const float* ln1w  = (const float*)d_in[1];
  const float* ln2w  = (const float*)d_in[2];
  const float* qkvw  = (const float*)d_in[3];
  const float* ow    = (const float*)d_in[4];
  const float* gatew = (const float*)d_in[5];
  const float* upw   = (const float*)d_in[6];
  const float* downw = (const float*)d_in[7];

  uint8_t* ws = (uint8_t*)d_ws;
  // workspace layout (bytes); ~80 MB total with aliasing
  bf16* WQKV = (bf16*)(ws + 0);          // 6291456
  bf16* WO   = (bf16*)(ws + 6291456);    // 2097152
  bf16* WG   = (bf16*)(ws + 8388608);    // 4194304  (WU must follow contiguously)
  bf16* WU   = (bf16*)(ws + 12582912);   // 4194304
  bf16* WD   = (bf16*)(ws + 16777216);   // 4194304
  bf16* H    = (bf16*)(ws + 20971520);   // 8388608
  bf16* Q    = (bf16*)(ws + 29360128);   // 8388608
  bf16* Kb   = (bf16*)(ws + 37748736);   // 8388608
  bf16* VT   = (bf16*)(ws + 46137344);   // 8388608  (B,H,64,T)
  bf16* Y    = (bf16*)(ws + 54525952);   // 8388608
  float* X2  = (float*)(ws + 62914560);  // 16777216 -> end 79691776
  // FFN phase aliases (Q/Kb/VT/Y dead after o-proj):
  bf16* G = (bf16*)(ws + 29360128);      // 16777216 (4096 x 2048)
  bf16* U = (bf16*)(ws + 46137344);      // 16777216 (4096 x 2048)
  // attn-phase aliases (dead regions during attention):
  unsigned short* pO = (unsigned short*)(ws + 62914560);  // 2x8MB partial O (X2 region)
  float* pL = (float*)(ws + 20971520);                    // 2x256KB partial lsum (H region)

  // weights -> bf16
  f2b_k<<<3072, 256, 0, stream>>>(qkvw, WQKV, 3072 * 1024);
  f2b_k<<<1024, 256, 0, stream>>>(ow, WO, 1024 * 1024);
  f2b_k<<<2048, 256, 0, stream>>>(gatew, WG, 2048 * 1024);
  f2b_k<<<2048, 256, 0, stream>>>(upw, WU, 2048 * 1024);
  f2b_k<<<2048, 256, 0, stream>>>(downw, WD, 1024 * 2048);

  // attn path
  rms_k<<<MROWS, 256, 0, stream>>>(x, ln1w, H);
  gemm_bt<1024, 1><<<dim3(24, 32), 256, 0, stream>>>(H, WQKV, 3072, Q, Kb, VT, nullptr);
  attn_k<<<1024, 256, 0, stream>>>(Q, Kb, VT, pO, pL);
  comb_k<<<4096, 256, 0, stream>>>(pO, pL, Y);
  gemm_bt<1024, 2><<<dim3(8, 32), 256, 0, stream>>>(Y, WO, 1024, X2, nullptr, nullptr, x);

  // ffn path (gate+up fused: WG||WU contiguous = (4096,1024) weight)
  rms_k<<<MROWS, 256, 0, stream>>>(X2, ln2w, H);
  gemm_bt<1024, 3><<<dim3(32, 32), 256, 0, stream>>>(H, WG, 4096, G, U, nullptr, nullptr);
  silumul_k<<<8192, 256, 0, stream>>>(G, U, G, 4096 * 2048);
  gemm_bt<2048, 2><<<dim3(8, 32), 256, 0, stream>>>(G, WD, 1024, (float*)d_out, nullptr, nullptr, X2);
}

// Round 8
// 254.579 us; speedup vs baseline: 1.2597x; 1.2597x over previous
//
#include <hip/hip_runtime.h>
#include <hip/hip_bf16.h>
#include <cstdint>

typedef __hip_bfloat16 bf16;
typedef __attribute__((ext_vector_type(8))) short bf16x8;
typedef __attribute__((ext_vector_type(4))) float f32x4;
typedef __attribute__((ext_vector_type(4))) int i32x4;

#define T_SEQ 2048
#define DMODEL 1024
#define NHEAD 16
#define DHEAD 64
#define MROWS 4096

typedef const __attribute__((address_space(1))) void* gas_ptr;
typedef __attribute__((address_space(3))) void* las_ptr;

static __device__ __forceinline__ f32x4 mfma16(bf16x8 a, bf16x8 b, f32x4 c) {
  return __builtin_amdgcn_mfma_f32_16x16x32_bf16(a, b, c, 0, 0, 0);
}
static __device__ __forceinline__ void gload_lds16(const void* g, void* l) {
  __builtin_amdgcn_global_load_lds((gas_ptr)g, (las_ptr)l, 16, 0, 0);
}
static __device__ __forceinline__ float b2f(unsigned short u) {
  union { unsigned int i; float f; } x; x.i = ((unsigned int)u) << 16; return x.f;
}
static __device__ __forceinline__ unsigned short f2bu(float f) {
  __hip_bfloat16 h = __float2bfloat16(f);
  unsigned short u; __builtin_memcpy(&u, &h, 2); return u;
}

// ---------------- weight fp32 -> bf16 ----------------
__global__ void f2b_k(const float* __restrict__ in, bf16* __restrict__ out, int n) {
  int idx = (blockIdx.x * blockDim.x + threadIdx.x) * 4;
  if (idx < n) {
    float4 v = *(const float4*)(in + idx);
    out[idx]     = __float2bfloat16(v.x);
    out[idx + 1] = __float2bfloat16(v.y);
    out[idx + 2] = __float2bfloat16(v.z);
    out[idx + 3] = __float2bfloat16(v.w);
  }
}

// ---------------- RMSNorm: fp32 in -> bf16 out ----------------
__global__ __launch_bounds__(256) void rms_k(const float* __restrict__ x,
                                             const float* __restrict__ w,
                                             bf16* __restrict__ out) {
  const int row = blockIdx.x;
  const int tid = threadIdx.x;
  const float4 v = ((const float4*)(x + (size_t)row * DMODEL))[tid];
  float ss = v.x * v.x + v.y * v.y + v.z * v.z + v.w * v.w;
#pragma unroll
  for (int off = 32; off; off >>= 1) ss += __shfl_xor(ss, off);
  __shared__ float red[4];
  if ((tid & 63) == 0) red[tid >> 6] = ss;
  __syncthreads();
  const float tot = red[0] + red[1] + red[2] + red[3];
  const float rinv = rsqrtf(tot * (1.f / DMODEL) + 1e-6f);
  const float4 wv = ((const float4*)w)[tid];
  bf16* o = out + (size_t)row * DMODEL + tid * 4;
  o[0] = __float2bfloat16(v.x * rinv * wv.x);
  o[1] = __float2bfloat16(v.y * rinv * wv.y);
  o[2] = __float2bfloat16(v.z * rinv * wv.z);
  o[3] = __float2bfloat16(v.w * rinv * wv.w);
}

// ---------------- GEMM: C = A(M,K) x Bw(N,K)^T, bf16 in, fp32 accum ----------------
// m97 structure: 128x128 tile, BK=32, 4 waves, global_load_lds width=16.
// EPI: 0 = bf16 store to o0 (ld=N)
//      1 = qkv scatter: Q,K as (B,H,T,64) to o0/o1; V TRANSPOSED as (B,H,64,T) to o2
//      2 = fp32 store o0 = res + C (ld=N)
//      3 = split-N: cols [0,N/2) -> o0, [N/2,N) -> o1, each compact ld=N/2 bf16
template <int K, int EPI>
__global__ __launch_bounds__(256) void gemm_bt(const bf16* __restrict__ A,
                                               const bf16* __restrict__ Bw, int N,
                                               void* __restrict__ o0, void* __restrict__ o1,
                                               void* __restrict__ o2,
                                               const float* __restrict__ res) {
  __shared__ bf16 As[128 * 32];
  __shared__ bf16 Bs[128 * 32];
  const int bn0 = blockIdx.x * 128;
  const int bm0 = blockIdx.y * 128;
  const int tid = threadIdx.x;
  const int wave = tid >> 6, lane = tid & 63;
  const int wr = wave >> 1, wc = wave & 1;
  const int fr = lane & 15, g8 = (lane >> 4) * 8, r4 = (lane >> 4) * 4;
  const int srow = lane >> 2;
  const int scol = (lane & 3) * 8;

  const f32x4 fzero = {0.f, 0.f, 0.f, 0.f};
  f32x4 acc[4][4];
#pragma unroll
  for (int i = 0; i < 4; i++)
#pragma unroll
    for (int j = 0; j < 4; j++) acc[i][j] = fzero;

  const bf16* gA0 = A + (size_t)(bm0 + wave * 16 + srow) * K + scol;
  const bf16* gA1 = A + (size_t)(bm0 + (wave + 4) * 16 + srow) * K + scol;
  const bf16* gB0 = Bw + (size_t)(bn0 + wave * 16 + srow) * K + scol;
  const bf16* gB1 = Bw + (size_t)(bn0 + (wave + 4) * 16 + srow) * K + scol;

  for (int k0 = 0; k0 < K; k0 += 32) {
    gload_lds16(gA0 + k0, &As[wave * 512]);
    gload_lds16(gA1 + k0, &As[(wave + 4) * 512]);
    gload_lds16(gB0 + k0, &Bs[wave * 512]);
    gload_lds16(gB1 + k0, &Bs[(wave + 4) * 512]);
    __syncthreads();
    bf16x8 af[4], bfr[4];
#pragma unroll
    for (int mr = 0; mr < 4; mr++)
      af[mr] = *(const bf16x8*)&As[(wr * 64 + mr * 16 + fr) * 32 + g8];
#pragma unroll
    for (int nr = 0; nr < 4; nr++)
      bfr[nr] = *(const bf16x8*)&Bs[(wc * 64 + nr * 16 + fr) * 32 + g8];
#pragma unroll
    for (int mr = 0; mr < 4; mr++)
#pragma unroll
      for (int nr = 0; nr < 4; nr++)
        acc[mr][nr] = mfma16(af[mr], bfr[nr], acc[mr][nr]);
    __syncthreads();
  }

#pragma unroll
  for (int mr = 0; mr < 4; mr++) {
#pragma unroll
    for (int nr = 0; nr < 4; nr++) {
#pragma unroll
      for (int r = 0; r < 4; r++) {
        const int row = bm0 + wr * 64 + mr * 16 + r4 + r;
        const int col = bn0 + wc * 64 + nr * 16 + fr;
        const float vsum = acc[mr][nr][r];
        if (EPI == 0) {
          ((bf16*)o0)[(size_t)row * N + col] = __float2bfloat16(vsum);
        } else if (EPI == 1) {
          const int sel = col >> 10;
          const int n = col & 1023;
          const int h = n >> 6, d = n & 63;
          const int b = row >> 11, t = row & 2047;
          if (sel == 2) {
            // V transposed: (B,H,D,T)
            ((bf16*)o2)[(((size_t)(b * NHEAD + h)) * DHEAD + d) * T_SEQ + t] =
                __float2bfloat16(vsum);
          } else {
            bf16* dst = (sel == 0) ? (bf16*)o0 : (bf16*)o1;
            dst[(((size_t)(b * NHEAD + h)) * T_SEQ + t) * DHEAD + d] = __float2bfloat16(vsum);
          }
        } else if (EPI == 2) {
          ((float*)o0)[(size_t)row * N + col] = res[(size_t)row * N + col] + vsum;
        } else {
          const int half = N >> 1;
          bf16* dst = (col < half) ? (bf16*)o0 : (bf16*)o1;
          const int c = (col < half) ? col : col - half;
          dst[(size_t)row * half + c] = __float2bfloat16(vsum);
        }
      }
    }
  }
}

// ---------------- causal flash attention, block-shared K/V LDS staging -------
// Round 1/4/6/7 all ~126us regardless of structure => L2-BW bound on per-wave
// K/V fetch (~8.3 TB/s demand). Fix: 4 waves of a block share one K/V tile
// staged in LDS via global_load_lds (traffic /4).
// Grid 1024 blocks x 4 waves. Mapping: xcd=bid&7, j=bid>>3, bh=xcd*4+(j&3)
// (4 heads per XCD L2, r5-verified), qt=31-(j>>2) (heavy Q-tiles dispatch
// first). Block owns Q rows qt*64..qt*64+63; wave w owns rows qt*64+w*16..+15.
// All waves walk the SAME key range (uniform trip count nb=2qt+2); wave skips
// compute on tiles past its causal bound (<=2 tiles) but keeps barriers.
// Double-buffered: stage(ts+1) issued before compute(ts); ONE barrier/tile
// (syncthreads drains vmcnt->stage complete, lgkm->reads complete).
// LDS swizzle (rule #21 both-sides): K 16B-slot ^= (row&7), V slot ^= ((row>>1)&3),
// applied on pre-swizzled GLOBAL source and on the ds_read address -> 2-way
// bank aliasing only (free). Compute body = r6-verified swapped QK^T +
// register-shuffle P^T rebuild + unnormalized softmax; direct Y store.
__global__ __launch_bounds__(256) void attn_k(const bf16* __restrict__ qb,
                                              const bf16* __restrict__ kb,
                                              const bf16* __restrict__ vt,
                                              bf16* __restrict__ y) {
  const int wave = threadIdx.x >> 6, lane = threadIdx.x & 63;
  const int xcd = blockIdx.x & 7;
  const int j = blockIdx.x >> 3;
  const int bh = xcd * 4 + (j & 3);
  const int qt = 31 - (j >> 2);
  const int b = bh >> 4, h = bh & 15;
  const int fr = lane & 15, g8 = (lane >> 4) * 8, r4 = (lane >> 4) * 4;
  const int u = lane >> 4;                   // 16B slot index (0..3)
  const int src1 = fr + ((u & 1) << 5);      // P^T rebuild partner lanes
  const int src2 = src1 + 16;
  const bool hB = u >= 2;

  const bf16* qp = qb + (size_t)bh * T_SEQ * DHEAD;
  const bf16* kp = kb + (size_t)bh * T_SEQ * DHEAD;
  const bf16* vp = vt + (size_t)bh * DHEAD * T_SEQ;

  __shared__ char Ks[2][4096];  // 32 rows x 128B, slot-swizzled
  __shared__ char Vs[2][4096];  // 64 rows x 64B,  slot-swizzled

  const int q0 = qt * 64 + wave * 16;
  const int kend = q0 + 16;
  const int qrow = q0 + fr;
  const int nb = 2 * qt + 2;

  const bf16x8 qf0 = *(const bf16x8*)(qp + (size_t)(q0 + fr) * DHEAD + g8);
  const bf16x8 qf1 = *(const bf16x8*)(qp + (size_t)(q0 + fr) * DHEAD + 32 + g8);

  // staging lane geometry (source pre-swizzled so linear LDS dest = swizzled)
  const int krow_l = lane >> 3;                       // 0..7 within wave chunk
  const int kslot_l = (lane & 7) ^ krow_l;            // K src 16B slot
  const int vrow_l = lane >> 2;                       // 0..15 within wave chunk
  const int vslot_l = (lane & 3) ^ ((lane >> 3) & 3); // V src 16B slot

  // read-side swizzled LDS byte offsets
  const int kswz = (fr & 7) << 4;
  const int koffA = fr * 128 + ((u * 16) ^ kswz);
  const int koffB = fr * 128 + (((4 + u) * 16) ^ kswz);
  const int vswz = ((fr >> 1) & 3) << 4;

  const f32x4 fzero = {0.f, 0.f, 0.f, 0.f};
  f32x4 acc[4];
  float lpart = 0.f;
#pragma unroll
  for (int nf = 0; nf < 4; nf++) acc[nf] = fzero;

  // prologue: stage tile 0
  gload_lds16(kp + (size_t)(wave * 8 + krow_l) * DHEAD + kslot_l * 8,
              &Ks[0][wave * 1024]);
  gload_lds16(vp + (size_t)(wave * 16 + vrow_l) * T_SEQ + vslot_l * 8,
              &Vs[0][wave * 1024]);
  __syncthreads();

  for (int ts = 0; ts < nb; ++ts) {
    const int kt = ts * 32;
    const int buf = ts & 1;
    if (ts + 1 < nb) {  // block-uniform
      const int kn = kt + 32;
      gload_lds16(kp + (size_t)(kn + wave * 8 + krow_l) * DHEAD + kslot_l * 8,
                  &Ks[buf ^ 1][wave * 1024]);
      gload_lds16(vp + (size_t)(wave * 16 + vrow_l) * T_SEQ + kn + vslot_l * 8,
                  &Vs[buf ^ 1][wave * 1024]);
    }
    if (kt < kend) {  // wave-uniform causal skip
      const char* KB = Ks[buf];
      const char* VB = Vs[buf];
      const bf16x8 kf0a = *(const bf16x8*)(KB + koffA);
      const bf16x8 kf0b = *(const bf16x8*)(KB + koffB);
      const bf16x8 kf1a = *(const bf16x8*)(KB + 2048 + koffA);
      const bf16x8 kf1b = *(const bf16x8*)(KB + 2048 + koffB);
      bf16x8 vf[4];
#pragma unroll
      for (int nf = 0; nf < 4; nf++)
        vf[nf] = *(const bf16x8*)(VB + (nf * 16 + fr) * 64 + ((u * 16) ^ vswz));

      // swapped QK^T: S^T[k][q]; lane: q = fr, k_local = r4 + r (+16 for s1)
      f32x4 s0 = mfma16(kf0a, qf0, fzero);
      s0 = mfma16(kf0b, qf1, s0);
      f32x4 s1 = mfma16(kf1a, qf0, fzero);
      s1 = mfma16(kf1b, qf1, s1);

      float x0[4], x1[4];
      if (kt + 31 < q0) {  // fully below diagonal: no causal mask needed
#pragma unroll
        for (int r = 0; r < 4; r++) {
          x0[r] = __expf(fminf(s0[r] * 0.125f, 30.f));
          x1[r] = __expf(fminf(s1[r] * 0.125f, 30.f));
          lpart += x0[r] + x1[r];
        }
      } else {
#pragma unroll
        for (int r = 0; r < 4; r++) {
          const int k0 = kt + r4 + r;
          const int k1 = k0 + 16;
          x0[r] = (k0 <= qrow) ? __expf(fminf(s0[r] * 0.125f, 30.f)) : 0.f;
          x1[r] = (k1 <= qrow) ? __expf(fminf(s1[r] * 0.125f, 30.f)) : 0.f;
          lpart += x0[r] + x1[r];
        }
      }

      // pack P^T values (bf16 pairs along k)
      const int A01 = (int)((unsigned)f2bu(x0[0]) | ((unsigned)f2bu(x0[1]) << 16));
      const int A23 = (int)((unsigned)f2bu(x0[2]) | ((unsigned)f2bu(x0[3]) << 16));
      const int B01 = (int)((unsigned)f2bu(x1[0]) | ((unsigned)f2bu(x1[1]) << 16));
      const int B23 = (int)((unsigned)f2bu(x1[2]) | ((unsigned)f2bu(x1[3]) << 16));

      // rebuild B-frag P^T: dest lane (fr, u) needs k = 8*u .. 8*u+7
      const int t0a = __shfl(A01, src1), t0b = __shfl(B01, src1);
      const int t1a = __shfl(A23, src1), t1b = __shfl(B23, src1);
      const int t2a = __shfl(A01, src2), t2b = __shfl(B01, src2);
      const int t3a = __shfl(A23, src2), t3b = __shfl(B23, src2);
      i32x4 pw;
      pw[0] = hB ? t0b : t0a;
      pw[1] = hB ? t1b : t1a;
      pw[2] = hB ? t2b : t2a;
      pw[3] = hB ? t3b : t3a;
      const bf16x8 pb = __builtin_bit_cast(bf16x8, pw);

      // PV: O^T = V^T * P^T
#pragma unroll
      for (int nf = 0; nf < 4; nf++) acc[nf] = mfma16(vf[nf], pb, acc[nf]);
    }
    __syncthreads();  // stage(ts+1) done; reads of buf done before overwrite
  }

  // complete lsum for row q=fr: combine the 4 lanes holding its k-subsets
  lpart += __shfl_xor(lpart, 16);
  lpart += __shfl_xor(lpart, 32);
  const float inv = 1.f / lpart;

  // store O^T: lane (fr, u): t = q0+fr, d = nf*16 + r4 + 0..3 (8B stores)
  const int t = q0 + fr;
  unsigned short* yb =
      (unsigned short*)(y + (((size_t)(b * T_SEQ + t)) * NHEAD + h) * DHEAD);
#pragma unroll
  for (int nf = 0; nf < 4; nf++) {
    ushort4 ov;
    ov.x = f2bu(acc[nf][0] * inv);
    ov.y = f2bu(acc[nf][1] * inv);
    ov.z = f2bu(acc[nf][2] * inv);
    ov.w = f2bu(acc[nf][3] * inv);
    *(ushort4*)(yb + nf * 16 + r4) = ov;
  }
}

// ---------------- gu = silu(g) * u (bf16) ----------------
__global__ void silumul_k(const bf16* __restrict__ g, const bf16* __restrict__ u,
                          bf16* __restrict__ o, int n) {
  const int idx = (blockIdx.x * blockDim.x + threadIdx.x) * 4;
  if (idx < n) {
    const ushort4 gv = *(const ushort4*)((const unsigned short*)g + idx);
    const ushort4 uv = *(const ushort4*)((const unsigned short*)u + idx);
    ushort4 ov;
    float a, s;
    a = b2f(gv.x); s = a / (1.f + __expf(-a)); ov.x = f2bu(s * b2f(uv.x));
    a = b2f(gv.y); s = a / (1.f + __expf(-a)); ov.y = f2bu(s * b2f(uv.y));
    a = b2f(gv.z); s = a / (1.f + __expf(-a)); ov.z = f2bu(s * b2f(uv.z));
    a = b2f(gv.w); s = a / (1.f + __expf(-a)); ov.w = f2bu(s * b2f(uv.w));
    *(ushort4*)((unsigned short*)o + idx) = ov;
  }
}

// ---------------- launch ----------------
extern "C" void kernel_launch(void* const* d_in, const int* in_sizes, int n_in,
                              void* d_out, int out_size, void* d_ws, size_t ws_size,
                              hipStream_t stream) {
  const float* x     = (const float*)d_in[0];
  const float* ln1w  = (const float*)d_in[1];
  const float* ln2w  = (const float*)d_in[2];
  const float* qkvw  = (const float*)d_in[3];
  const float* ow    = (const float*)d_in[4];
  const float* gatew = (const float*)d_in[5];
  const float* upw   = (const float*)d_in[6];
  const float* downw = (const float*)d_in[7];

  uint8_t* ws = (uint8_t*)d_ws;
  // workspace layout (bytes); ~80 MB total with aliasing
  bf16* WQKV = (bf16*)(ws + 0);          // 6291456
  bf16* WO   = (bf16*)(ws + 6291456);    // 2097152
  bf16* WG   = (bf16*)(ws + 8388608);    // 4194304  (WU must follow contiguously)
  bf16* WU   = (bf16*)(ws + 12582912);   // 4194304
  bf16* WD   = (bf16*)(ws + 16777216);   // 4194304
  bf16* H    = (bf16*)(ws + 20971520);   // 8388608
  bf16* Q    = (bf16*)(ws + 29360128);   // 8388608
  bf16* Kb   = (bf16*)(ws + 37748736);   // 8388608
  bf16* VT   = (bf16*)(ws + 46137344);   // 8388608  (B,H,64,T)
  bf16* Y    = (bf16*)(ws + 54525952);   // 8388608
  float* X2  = (float*)(ws + 62914560);  // 16777216 -> end 79691776
  // FFN phase aliases (Q/Kb/VT/Y dead after o-proj):
  bf16* G = (bf16*)(ws + 29360128);      // 16777216 (4096 x 2048)
  bf16* U = (bf16*)(ws + 46137344);      // 16777216 (4096 x 2048)

  // weights -> bf16
  f2b_k<<<3072, 256, 0, stream>>>(qkvw, WQKV, 3072 * 1024);
  f2b_k<<<1024, 256, 0, stream>>>(ow, WO, 1024 * 1024);
  f2b_k<<<2048, 256, 0, stream>>>(gatew, WG, 2048 * 1024);
  f2b_k<<<2048, 256, 0, stream>>>(upw, WU, 2048 * 1024);
  f2b_k<<<2048, 256, 0, stream>>>(downw, WD, 1024 * 2048);

  // attn path
  rms_k<<<MROWS, 256, 0, stream>>>(x, ln1w, H);
  gemm_bt<1024, 1><<<dim3(24, 32), 256, 0, stream>>>(H, WQKV, 3072, Q, Kb, VT, nullptr);
  attn_k<<<1024, 256, 0, stream>>>(Q, Kb, VT, Y);
  gemm_bt<1024, 2><<<dim3(8, 32), 256, 0, stream>>>(Y, WO, 1024, X2, nullptr, nullptr, x);

  // ffn path (gate+up fused: WG||WU contiguous = (4096,1024) weight)
  rms_k<<<MROWS, 256, 0, stream>>>(X2, ln2w, H);
  gemm_bt<1024, 3><<<dim3(32, 32), 256, 0, stream>>>(H, WG, 4096, G, U, nullptr, nullptr);
  silumul_k<<<8192, 256, 0, stream>>>(G, U, G, 4096 * 2048);
  gemm_bt<2048, 2><<<dim3(8, 32), 256, 0, stream>>>(G, WD, 1024, (float*)d_out, nullptr, nullptr, X2);
}

// Round 9
// 242.820 us; speedup vs baseline: 1.3207x; 1.0484x over previous
//
#include <hip/hip_runtime.h>
#include <hip/hip_bf16.h>
#include <cstdint>

typedef __hip_bfloat16 bf16;
typedef __attribute__((ext_vector_type(8))) short bf16x8;
typedef __attribute__((ext_vector_type(4))) float f32x4;
typedef __attribute__((ext_vector_type(4))) int i32x4;

#define T_SEQ 2048
#define DMODEL 1024
#define NHEAD 16
#define DHEAD 64
#define MROWS 4096

typedef const __attribute__((address_space(1))) void* gas_ptr;
typedef __attribute__((address_space(3))) void* las_ptr;

static __device__ __forceinline__ f32x4 mfma16(bf16x8 a, bf16x8 b, f32x4 c) {
  return __builtin_amdgcn_mfma_f32_16x16x32_bf16(a, b, c, 0, 0, 0);
}
static __device__ __forceinline__ void gload_lds16(const void* g, void* l) {
  __builtin_amdgcn_global_load_lds((gas_ptr)g, (las_ptr)l, 16, 0, 0);
}
static __device__ __forceinline__ float b2f(unsigned short u) {
  union { unsigned int i; float f; } x; x.i = ((unsigned int)u) << 16; return x.f;
}
static __device__ __forceinline__ unsigned short f2bu(float f) {
  __hip_bfloat16 h = __float2bfloat16(f);
  unsigned short u; __builtin_memcpy(&u, &h, 2); return u;
}

// ------------- all weights fp32 -> bf16, ONE dispatch (dest contiguous) ------
__global__ __launch_bounds__(256) void f2ball_k(const float* __restrict__ a,
                                                const float* __restrict__ b,
                                                const float* __restrict__ c,
                                                const float* __restrict__ d,
                                                const float* __restrict__ e,
                                                bf16* __restrict__ out) {
  const int idx = (blockIdx.x * 256 + threadIdx.x) * 4;
  const float* src;
  int off;
  if (idx < 3145728)      { src = a; off = idx; }
  else if (idx < 4194304) { src = b; off = idx - 3145728; }
  else if (idx < 6291456) { src = c; off = idx - 4194304; }
  else if (idx < 8388608) { src = d; off = idx - 6291456; }
  else                    { src = e; off = idx - 8388608; }
  const float4 v = *(const float4*)(src + off);
  ushort4 ov;
  ov.x = f2bu(v.x); ov.y = f2bu(v.y); ov.z = f2bu(v.z); ov.w = f2bu(v.w);
  *(ushort4*)((unsigned short*)out + idx) = ov;
}

// ---------------- RMSNorm: fp32 in -> bf16 out ----------------
__global__ __launch_bounds__(256) void rms_k(const float* __restrict__ x,
                                             const float* __restrict__ w,
                                             bf16* __restrict__ out) {
  const int row = blockIdx.x;
  const int tid = threadIdx.x;
  const float4 v = ((const float4*)(x + (size_t)row * DMODEL))[tid];
  float ss = v.x * v.x + v.y * v.y + v.z * v.z + v.w * v.w;
#pragma unroll
  for (int off = 32; off; off >>= 1) ss += __shfl_xor(ss, off);
  __shared__ float red[4];
  if ((tid & 63) == 0) red[tid >> 6] = ss;
  __syncthreads();
  const float tot = red[0] + red[1] + red[2] + red[3];
  const float rinv = rsqrtf(tot * (1.f / DMODEL) + 1e-6f);
  const float4 wv = ((const float4*)w)[tid];
  bf16* o = out + (size_t)row * DMODEL + tid * 4;
  o[0] = __float2bfloat16(v.x * rinv * wv.x);
  o[1] = __float2bfloat16(v.y * rinv * wv.y);
  o[2] = __float2bfloat16(v.z * rinv * wv.z);
  o[3] = __float2bfloat16(v.w * rinv * wv.w);
}

// ---------------- GEMM: C = A(M,K) x Bw(N,K)^T, bf16 in, fp32 accum ----------------
// m97 structure: 128x128 tile, BK=32, 4 waves, global_load_lds width=16.
// EPI: 0 = bf16 store to o0 (ld=N)
//      1 = qkv scatter: Q,K as (B,H,T,64) to o0/o1; V TRANSPOSED as (B,H,64,T) to o2
//      2 = fp32 store o0 = res + C (ld=N)
//      3 = split-N: cols [0,N/2) -> o0, [N/2,N) -> o1, each compact ld=N/2 bf16
template <int K, int EPI>
__global__ __launch_bounds__(256) void gemm_bt(const bf16* __restrict__ A,
                                               const bf16* __restrict__ Bw, int N,
                                               void* __restrict__ o0, void* __restrict__ o1,
                                               void* __restrict__ o2,
                                               const float* __restrict__ res) {
  __shared__ bf16 As[128 * 32];
  __shared__ bf16 Bs[128 * 32];
  const int bn0 = blockIdx.x * 128;
  const int bm0 = blockIdx.y * 128;
  const int tid = threadIdx.x;
  const int wave = tid >> 6, lane = tid & 63;
  const int wr = wave >> 1, wc = wave & 1;
  const int fr = lane & 15, g8 = (lane >> 4) * 8, r4 = (lane >> 4) * 4;
  const int srow = lane >> 2;
  const int scol = (lane & 3) * 8;

  const f32x4 fzero = {0.f, 0.f, 0.f, 0.f};
  f32x4 acc[4][4];
#pragma unroll
  for (int i = 0; i < 4; i++)
#pragma unroll
    for (int j = 0; j < 4; j++) acc[i][j] = fzero;

  const bf16* gA0 = A + (size_t)(bm0 + wave * 16 + srow) * K + scol;
  const bf16* gA1 = A + (size_t)(bm0 + (wave + 4) * 16 + srow) * K + scol;
  const bf16* gB0 = Bw + (size_t)(bn0 + wave * 16 + srow) * K + scol;
  const bf16* gB1 = Bw + (size_t)(bn0 + (wave + 4) * 16 + srow) * K + scol;

  for (int k0 = 0; k0 < K; k0 += 32) {
    gload_lds16(gA0 + k0, &As[wave * 512]);
    gload_lds16(gA1 + k0, &As[(wave + 4) * 512]);
    gload_lds16(gB0 + k0, &Bs[wave * 512]);
    gload_lds16(gB1 + k0, &Bs[(wave + 4) * 512]);
    __syncthreads();
    bf16x8 af[4], bfr[4];
#pragma unroll
    for (int mr = 0; mr < 4; mr++)
      af[mr] = *(const bf16x8*)&As[(wr * 64 + mr * 16 + fr) * 32 + g8];
#pragma unroll
    for (int nr = 0; nr < 4; nr++)
      bfr[nr] = *(const bf16x8*)&Bs[(wc * 64 + nr * 16 + fr) * 32 + g8];
#pragma unroll
    for (int mr = 0; mr < 4; mr++)
#pragma unroll
      for (int nr = 0; nr < 4; nr++)
        acc[mr][nr] = mfma16(af[mr], bfr[nr], acc[mr][nr]);
    __syncthreads();
  }

#pragma unroll
  for (int mr = 0; mr < 4; mr++) {
#pragma unroll
    for (int nr = 0; nr < 4; nr++) {
#pragma unroll
      for (int r = 0; r < 4; r++) {
        const int row = bm0 + wr * 64 + mr * 16 + r4 + r;
        const int col = bn0 + wc * 64 + nr * 16 + fr;
        const float vsum = acc[mr][nr][r];
        if (EPI == 0) {
          ((bf16*)o0)[(size_t)row * N + col] = __float2bfloat16(vsum);
        } else if (EPI == 1) {
          const int sel = col >> 10;
          const int n = col & 1023;
          const int h = n >> 6, d = n & 63;
          const int b = row >> 11, t = row & 2047;
          if (sel == 2) {
            // V transposed: (B,H,D,T)
            ((bf16*)o2)[(((size_t)(b * NHEAD + h)) * DHEAD + d) * T_SEQ + t] =
                __float2bfloat16(vsum);
          } else {
            bf16* dst = (sel == 0) ? (bf16*)o0 : (bf16*)o1;
            dst[(((size_t)(b * NHEAD + h)) * T_SEQ + t) * DHEAD + d] = __float2bfloat16(vsum);
          }
        } else if (EPI == 2) {
          ((float*)o0)[(size_t)row * N + col] = res[(size_t)row * N + col] + vsum;
        } else {
          const int half = N >> 1;
          bf16* dst = (col < half) ? (bf16*)o0 : (bf16*)o1;
          const int c = (col < half) ? col : col - half;
          dst[(size_t)row * half + c] = __float2bfloat16(vsum);
        }
      }
    }
  }
}

// ---------------- causal flash attention, shared LDS staging + heavy key-split
// r8 proved L2-BW fix (LDS sharing, 128->62us) but avg occupancy 25%: block
// duration ~ qt+1 (2..64 steps) -> drain tail. Fix: split keys of heavy
// Q-tiles (qt>=16) across TWO blocks (additive partials, r7-proven — the
// unnormalized softmax has no running max). All blocks now run <=32 steps:
//   heavy (bid<1024): c=bid&7, r=bid>>3, bh=c*4+(r&3), idx=r>>2,
//     qt=31-(idx>>1), hs=idx&1; tiles [hs*(qt+1), (hs+1)*(qt+1)), nb=qt+1.
//     -> RAW bf16 partial O + f32 lsum to slot hs; comb_k merges.
//   light (bid>=1024): qt=15-..., nb=2qt+2, full range, direct Y store.
// 1536 blocks x 4 waves = 6144 waves (75% cap), heavy-qt-first dispatch.
// Staging/swizzle/compute body byte-identical to r8 (verified).
__global__ __launch_bounds__(256) void attn_k(const bf16* __restrict__ qb,
                                              const bf16* __restrict__ kb,
                                              const bf16* __restrict__ vt,
                                              bf16* __restrict__ y,
                                              unsigned short* __restrict__ pO,
                                              float* __restrict__ pL) {
  const int wave = threadIdx.x >> 6, lane = threadIdx.x & 63;
  const int bid = blockIdx.x;
  int bh, qt, ks0, nb, heavy, hs;
  if (bid < 1024) {
    const int c = bid & 7, r = bid >> 3;
    bh = c * 4 + (r & 3);
    const int idx = r >> 2;
    qt = 31 - (idx >> 1);
    hs = idx & 1;
    heavy = 1;
    nb = qt + 1;
    ks0 = hs * nb;
  } else {
    const int bd = bid - 1024;
    const int c = bd & 7, r = bd >> 3;
    bh = c * 4 + (r & 3);
    qt = 15 - (r >> 2);
    hs = 0;
    heavy = 0;
    nb = 2 * qt + 2;
    ks0 = 0;
  }
  const int b = bh >> 4, h = bh & 15;
  const int fr = lane & 15, g8 = (lane >> 4) * 8, r4 = (lane >> 4) * 4;
  const int u = lane >> 4;
  const int src1 = fr + ((u & 1) << 5);
  const int src2 = src1 + 16;
  const bool hB = u >= 2;

  const bf16* qp = qb + (size_t)bh * T_SEQ * DHEAD;
  const bf16* kp = kb + (size_t)bh * T_SEQ * DHEAD;
  const bf16* vp = vt + (size_t)bh * DHEAD * T_SEQ;

  __shared__ char Ks[2][4096];  // 32 rows x 128B, slot-swizzled
  __shared__ char Vs[2][4096];  // 64 rows x 64B,  slot-swizzled

  const int q0 = qt * 64 + wave * 16;
  const int kend = q0 + 16;
  const int qrow = q0 + fr;

  const bf16x8 qf0 = *(const bf16x8*)(qp + (size_t)(q0 + fr) * DHEAD + g8);
  const bf16x8 qf1 = *(const bf16x8*)(qp + (size_t)(q0 + fr) * DHEAD + 32 + g8);

  // staging lane geometry (source pre-swizzled so linear LDS dest = swizzled)
  const int krow_l = lane >> 3;
  const int kslot_l = (lane & 7) ^ krow_l;
  const int vrow_l = lane >> 2;
  const int vslot_l = (lane & 3) ^ ((lane >> 3) & 3);

  // read-side swizzled LDS byte offsets
  const int kswz = (fr & 7) << 4;
  const int koffA = fr * 128 + ((u * 16) ^ kswz);
  const int koffB = fr * 128 + (((4 + u) * 16) ^ kswz);
  const int vswz = ((fr >> 1) & 3) << 4;

  const f32x4 fzero = {0.f, 0.f, 0.f, 0.f};
  f32x4 acc[4];
  float lpart = 0.f;
#pragma unroll
  for (int nf = 0; nf < 4; nf++) acc[nf] = fzero;

  // prologue: stage first tile
  gload_lds16(kp + (size_t)(ks0 * 32 + wave * 8 + krow_l) * DHEAD + kslot_l * 8,
              &Ks[0][wave * 1024]);
  gload_lds16(vp + (size_t)(wave * 16 + vrow_l) * T_SEQ + ks0 * 32 + vslot_l * 8,
              &Vs[0][wave * 1024]);
  __syncthreads();

  for (int ts = 0; ts < nb; ++ts) {
    const int kt = (ks0 + ts) * 32;
    const int buf = ts & 1;
    if (ts + 1 < nb) {  // block-uniform
      const int kn = kt + 32;
      gload_lds16(kp + (size_t)(kn + wave * 8 + krow_l) * DHEAD + kslot_l * 8,
                  &Ks[buf ^ 1][wave * 1024]);
      gload_lds16(vp + (size_t)(wave * 16 + vrow_l) * T_SEQ + kn + vslot_l * 8,
                  &Vs[buf ^ 1][wave * 1024]);
    }
    if (kt < kend) {  // wave-uniform causal skip
      const char* KB = Ks[buf];
      const char* VB = Vs[buf];
      const bf16x8 kf0a = *(const bf16x8*)(KB + koffA);
      const bf16x8 kf0b = *(const bf16x8*)(KB + koffB);
      const bf16x8 kf1a = *(const bf16x8*)(KB + 2048 + koffA);
      const bf16x8 kf1b = *(const bf16x8*)(KB + 2048 + koffB);
      bf16x8 vf[4];
#pragma unroll
      for (int nf = 0; nf < 4; nf++)
        vf[nf] = *(const bf16x8*)(VB + (nf * 16 + fr) * 64 + ((u * 16) ^ vswz));

      // swapped QK^T: S^T[k][q]; lane: q = fr, k_local = r4 + r (+16 for s1)
      f32x4 s0 = mfma16(kf0a, qf0, fzero);
      s0 = mfma16(kf0b, qf1, s0);
      f32x4 s1 = mfma16(kf1a, qf0, fzero);
      s1 = mfma16(kf1b, qf1, s1);

      float x0[4], x1[4];
      if (kt + 31 < q0) {  // fully below diagonal: no causal mask needed
#pragma unroll
        for (int r = 0; r < 4; r++) {
          x0[r] = __expf(fminf(s0[r] * 0.125f, 30.f));
          x1[r] = __expf(fminf(s1[r] * 0.125f, 30.f));
          lpart += x0[r] + x1[r];
        }
      } else {
#pragma unroll
        for (int r = 0; r < 4; r++) {
          const int k0 = kt + r4 + r;
          const int k1 = k0 + 16;
          x0[r] = (k0 <= qrow) ? __expf(fminf(s0[r] * 0.125f, 30.f)) : 0.f;
          x1[r] = (k1 <= qrow) ? __expf(fminf(s1[r] * 0.125f, 30.f)) : 0.f;
          lpart += x0[r] + x1[r];
        }
      }

      // pack P^T values (bf16 pairs along k)
      const int A01 = (int)((unsigned)f2bu(x0[0]) | ((unsigned)f2bu(x0[1]) << 16));
      const int A23 = (int)((unsigned)f2bu(x0[2]) | ((unsigned)f2bu(x0[3]) << 16));
      const int B01 = (int)((unsigned)f2bu(x1[0]) | ((unsigned)f2bu(x1[1]) << 16));
      const int B23 = (int)((unsigned)f2bu(x1[2]) | ((unsigned)f2bu(x1[3]) << 16));

      // rebuild B-frag P^T: dest lane (fr, u) needs k = 8*u .. 8*u+7
      const int t0a = __shfl(A01, src1), t0b = __shfl(B01, src1);
      const int t1a = __shfl(A23, src1), t1b = __shfl(B23, src1);
      const int t2a = __shfl(A01, src2), t2b = __shfl(B01, src2);
      const int t3a = __shfl(A23, src2), t3b = __shfl(B23, src2);
      i32x4 pw;
      pw[0] = hB ? t0b : t0a;
      pw[1] = hB ? t1b : t1a;
      pw[2] = hB ? t2b : t2a;
      pw[3] = hB ? t3b : t3a;
      const bf16x8 pb = __builtin_bit_cast(bf16x8, pw);

      // PV: O^T (partial) = V^T * P^T
#pragma unroll
      for (int nf = 0; nf < 4; nf++) acc[nf] = mfma16(vf[nf], pb, acc[nf]);
    }
    __syncthreads();  // stage(ts+1) done; reads of buf done before overwrite
  }

  // per-row k-subset combine across the 4 lanes sharing fr
  lpart += __shfl_xor(lpart, 16);
  lpart += __shfl_xor(lpart, 32);

  if (!heavy) {
    const float inv = 1.f / lpart;
    const int t = q0 + fr;
    unsigned short* yb =
        (unsigned short*)(y + (((size_t)(b * T_SEQ + t)) * NHEAD + h) * DHEAD);
#pragma unroll
    for (int nf = 0; nf < 4; nf++) {
      ushort4 ov;
      ov.x = f2bu(acc[nf][0] * inv);
      ov.y = f2bu(acc[nf][1] * inv);
      ov.z = f2bu(acc[nf][2] * inv);
      ov.w = f2bu(acc[nf][3] * inv);
      *(ushort4*)(yb + nf * 16 + r4) = ov;
    }
  } else {
    // raw partials to slot hs (rows 1024..2047 -> local 0..1023)
    const int tl = q0 - 1024 + fr;
    unsigned short* po = pO + ((size_t)(hs * 32 + bh) * 1024 + tl) * DHEAD;
#pragma unroll
    for (int nf = 0; nf < 4; nf++) {
      ushort4 ov;
      ov.x = f2bu(acc[nf][0]);
      ov.y = f2bu(acc[nf][1]);
      ov.z = f2bu(acc[nf][2]);
      ov.w = f2bu(acc[nf][3]);
      *(ushort4*)(po + nf * 16 + r4) = ov;
    }
    if (lane < 16) pL[(size_t)(hs * 32 + bh) * 1024 + (q0 - 1024) + lane] = lpart;
  }
}

// ---------------- combine heavy partials -> Y rows 1024..2047 ----------------
__global__ __launch_bounds__(256) void comb_k(const unsigned short* __restrict__ pO,
                                              const float* __restrict__ pL,
                                              bf16* __restrict__ y) {
  const int idx = blockIdx.x * 256 + threadIdx.x;  // 16 threads per row
  const int row = idx >> 4;                        // bh*1024 + tl
  const int d0 = (idx & 15) * 4;
  const int bh = row >> 10, tl = row & 1023;
  const int b = bh >> 4, h = bh & 15;
  const int t = 1024 + tl;
  const float inv = 1.f / (pL[row] + pL[32768 + row]);
  const ushort4 a = *(const ushort4*)(pO + (size_t)row * DHEAD + d0);
  const ushort4 c = *(const ushort4*)(pO + (size_t)(32768 + row) * DHEAD + d0);
  ushort4 ov;
  ov.x = f2bu((b2f(a.x) + b2f(c.x)) * inv);
  ov.y = f2bu((b2f(a.y) + b2f(c.y)) * inv);
  ov.z = f2bu((b2f(a.z) + b2f(c.z)) * inv);
  ov.w = f2bu((b2f(a.w) + b2f(c.w)) * inv);
  *(ushort4*)((unsigned short*)y + (((size_t)(b * T_SEQ + t)) * NHEAD + h) * DHEAD + d0) = ov;
}

// ---------------- gu = silu(g) * u (bf16) ----------------
__global__ void silumul_k(const bf16* __restrict__ g, const bf16* __restrict__ u,
                          bf16* __restrict__ o, int n) {
  const int idx = (blockIdx.x * blockDim.x + threadIdx.x) * 4;
  if (idx < n) {
    const ushort4 gv = *(const ushort4*)((const unsigned short*)g + idx);
    const ushort4 uv = *(const ushort4*)((const unsigned short*)u + idx);
    ushort4 ov;
    float a, s;
    a = b2f(gv.x); s = a / (1.f + __expf(-a)); ov.x = f2bu(s * b2f(uv.x));
    a = b2f(gv.y); s = a / (1.f + __expf(-a)); ov.y = f2bu(s * b2f(uv.y));
    a = b2f(gv.z); s = a / (1.f + __expf(-a)); ov.z = f2bu(s * b2f(uv.z));
    a = b2f(gv.w); s = a / (1.f + __expf(-a)); ov.w = f2bu(s * b2f(uv.w));
    *(ushort4*)((unsigned short*)o + idx) = ov;
  }
}

// ---------------- launch ----------------
extern "C" void kernel_launch(void* const* d_in, const int* in_sizes, int n_in,
                              void* d_out, int out_size, void* d_ws, size_t ws_size,
                              hipStream_t stream) {
  const float* x     = (const float*)d_in[0];
  const float* ln1w  = (const float*)d_in[1];
  const float* ln2w  = (const float*)d_in[2];
  const float* qkvw  = (const float*)d_in[3];
  const float* ow    = (const float*)d_in[4];
  const float* gatew = (const float*)d_in[5];
  const float* upw   = (const float*)d_in[6];
  const float* downw = (const float*)d_in[7];

  uint8_t* ws = (uint8_t*)d_ws;
  // workspace layout (bytes); ~80 MB total with aliasing
  bf16* WQKV = (bf16*)(ws + 0);          // 6291456
  bf16* WO   = (bf16*)(ws + 6291456);    // 2097152
  bf16* WG   = (bf16*)(ws + 8388608);    // 4194304  (WU must follow contiguously)
  bf16* WU   = (bf16*)(ws + 12582912);   // 4194304
  bf16* WD   = (bf16*)(ws + 16777216);   // 4194304
  bf16* H    = (bf16*)(ws + 20971520);   // 8388608
  bf16* Q    = (bf16*)(ws + 29360128);   // 8388608
  bf16* Kb   = (bf16*)(ws + 37748736);   // 8388608
  bf16* VT   = (bf16*)(ws + 46137344);   // 8388608  (B,H,64,T)
  bf16* Y    = (bf16*)(ws + 54525952);   // 8388608
  float* X2  = (float*)(ws + 62914560);  // 16777216 -> end 79691776
  // FFN phase aliases (Q/Kb/VT/Y dead after o-proj):
  bf16* G = (bf16*)(ws + 29360128);      // 16777216 (4096 x 2048)
  bf16* U = (bf16*)(ws + 46137344);      // 16777216 (4096 x 2048)
  // attn-phase aliases (dead regions during attention):
  unsigned short* pO = (unsigned short*)(ws + 62914560);  // 8MB partials (X2 region)
  float* pL = (float*)(ws + 20971520);                    // 256KB lsums (H region)

  // weights -> bf16 (single dispatch; dest = ws[0..20971520) contiguous)
  f2ball_k<<<10240, 256, 0, stream>>>(qkvw, ow, gatew, upw, downw, (bf16*)ws);

  // attn path
  rms_k<<<MROWS, 256, 0, stream>>>(x, ln1w, H);
  gemm_bt<1024, 1><<<dim3(24, 32), 256, 0, stream>>>(H, WQKV, 3072, Q, Kb, VT, nullptr);
  attn_k<<<1536, 256, 0, stream>>>(Q, Kb, VT, Y, pO, pL);
  comb_k<<<2048, 256, 0, stream>>>(pO, pL, Y);
  gemm_bt<1024, 2><<<dim3(8, 32), 256, 0, stream>>>(Y, WO, 1024, X2, nullptr, nullptr, x);

  // ffn path (gate+up fused: WG||WU contiguous = (4096,1024) weight)
  rms_k<<<MROWS, 256, 0, stream>>>(X2, ln2w, H);
  gemm_bt<1024, 3><<<dim3(32, 32), 256, 0, stream>>>(H, WG, 4096, G, U, nullptr, nullptr);
  silumul_k<<<8192, 256, 0, stream>>>(G, U, G, 4096 * 2048);
  gemm_bt<2048, 2><<<dim3(8, 32), 256, 0, stream>>>(G, WD, 1024, (float*)d_out, nullptr, nullptr, X2);
}

// Round 10
// 234.612 us; speedup vs baseline: 1.3669x; 1.0350x over previous
//
#include <hip/hip_runtime.h>
#include <hip/hip_bf16.h>
#include <cstdint>

typedef __hip_bfloat16 bf16;
typedef __attribute__((ext_vector_type(8))) short bf16x8;
typedef __attribute__((ext_vector_type(4))) float f32x4;
typedef __attribute__((ext_vector_type(4))) int i32x4;

#define T_SEQ 2048
#define DMODEL 1024
#define NHEAD 16
#define DHEAD 64
#define MROWS 4096

typedef const __attribute__((address_space(1))) void* gas_ptr;
typedef __attribute__((address_space(3))) void* las_ptr;

static __device__ __forceinline__ f32x4 mfma16(bf16x8 a, bf16x8 b, f32x4 c) {
  return __builtin_amdgcn_mfma_f32_16x16x32_bf16(a, b, c, 0, 0, 0);
}
static __device__ __forceinline__ void gload_lds16(const void* g, void* l) {
  __builtin_amdgcn_global_load_lds((gas_ptr)g, (las_ptr)l, 16, 0, 0);
}
static __device__ __forceinline__ float b2f(unsigned short u) {
  union { unsigned int i; float f; } x; x.i = ((unsigned int)u) << 16; return x.f;
}
static __device__ __forceinline__ unsigned short f2bu(float f) {
  __hip_bfloat16 h = __float2bfloat16(f);
  unsigned short u; __builtin_memcpy(&u, &h, 2); return u;
}

// ------------- all weights fp32 -> bf16, ONE dispatch (dest contiguous) ------
// gate/up rows are INTERLEAVED into WGU: row 2i = gate_i, row 2i+1 = up_i,
// so the fused gate+up GEMM can combine g/u in-register (silu epilogue).
__global__ __launch_bounds__(256) void f2ball_k(const float* __restrict__ a,
                                                const float* __restrict__ b,
                                                const float* __restrict__ c,
                                                const float* __restrict__ d,
                                                const float* __restrict__ e,
                                                bf16* __restrict__ out) {
  const int idx = (blockIdx.x * 256 + threadIdx.x) * 4;
  const float* src;
  int off, dst;
  if (idx < 3145728) {                     // qkv
    src = a; off = idx; dst = idx;
  } else if (idx < 4194304) {              // o
    src = b; off = idx - 3145728; dst = idx;
  } else if (idx < 6291456) {              // gate -> WGU even rows
    src = c; off = idx - 4194304;
    dst = 4194304 + ((off >> 10) << 11) + (off & 1023);
  } else if (idx < 8388608) {              // up -> WGU odd rows
    src = d; off = idx - 6291456;
    dst = 4194304 + ((off >> 10) << 11) + 1024 + (off & 1023);
  } else {                                 // down
    src = e; off = idx - 8388608; dst = idx;
  }
  const float4 v = *(const float4*)(src + off);
  ushort4 ov;
  ov.x = f2bu(v.x); ov.y = f2bu(v.y); ov.z = f2bu(v.z); ov.w = f2bu(v.w);
  *(ushort4*)((unsigned short*)out + dst) = ov;
}

// ---------------- RMSNorm: fp32 in -> bf16 out ----------------
__global__ __launch_bounds__(256) void rms_k(const float* __restrict__ x,
                                             const float* __restrict__ w,
                                             bf16* __restrict__ out) {
  const int row = blockIdx.x;
  const int tid = threadIdx.x;
  const float4 v = ((const float4*)(x + (size_t)row * DMODEL))[tid];
  float ss = v.x * v.x + v.y * v.y + v.z * v.z + v.w * v.w;
#pragma unroll
  for (int off = 32; off; off >>= 1) ss += __shfl_xor(ss, off);
  __shared__ float red[4];
  if ((tid & 63) == 0) red[tid >> 6] = ss;
  __syncthreads();
  const float tot = red[0] + red[1] + red[2] + red[3];
  const float rinv = rsqrtf(tot * (1.f / DMODEL) + 1e-6f);
  const float4 wv = ((const float4*)w)[tid];
  bf16* o = out + (size_t)row * DMODEL + tid * 4;
  o[0] = __float2bfloat16(v.x * rinv * wv.x);
  o[1] = __float2bfloat16(v.y * rinv * wv.y);
  o[2] = __float2bfloat16(v.z * rinv * wv.z);
  o[3] = __float2bfloat16(v.w * rinv * wv.w);
}

// ---------------- GEMM: C = A(M,K) x Bw(N,K)^T, bf16 in, fp32 accum ----------------
// m97 structure: 128x128 tile, BK=32, 4 waves, global_load_lds width=16.
// Bijective XCD swizzle on the flat block index (all grids have nwg%8==0).
// EPI: 0 = bf16 store to o0 (ld=N)
//      1 = qkv scatter: Q,K as (B,H,T,64) to o0/o1; V TRANSPOSED as (B,H,64,T) to o2
//      2 = fp32 store o0 = res + C (ld=N)
//      4 = fused gate/up (B = row-interleaved WGU): even col=gate, odd col=up;
//          even lanes compute silu(g)*u -> bf16 store to o0 (ld = N/2)
template <int K, int EPI>
__global__ __launch_bounds__(256) void gemm_bt(const bf16* __restrict__ A,
                                               const bf16* __restrict__ Bw, int N,
                                               void* __restrict__ o0, void* __restrict__ o1,
                                               void* __restrict__ o2,
                                               const float* __restrict__ res) {
  __shared__ bf16 As[128 * 32];
  __shared__ bf16 Bs[128 * 32];
  // XCD-aware block remap (contiguous chunk per XCD)
  const int nbx = gridDim.x;
  const int nwg = nbx * gridDim.y;
  int fb = blockIdx.y * nbx + blockIdx.x;
  fb = (fb & 7) * (nwg >> 3) + (fb >> 3);
  const int bn0 = (fb % nbx) * 128;
  const int bm0 = (fb / nbx) * 128;
  const int tid = threadIdx.x;
  const int wave = tid >> 6, lane = tid & 63;
  const int wr = wave >> 1, wc = wave & 1;
  const int fr = lane & 15, g8 = (lane >> 4) * 8, r4 = (lane >> 4) * 4;
  const int srow = lane >> 2;
  const int scol = (lane & 3) * 8;

  const f32x4 fzero = {0.f, 0.f, 0.f, 0.f};
  f32x4 acc[4][4];
#pragma unroll
  for (int i = 0; i < 4; i++)
#pragma unroll
    for (int j = 0; j < 4; j++) acc[i][j] = fzero;

  const bf16* gA0 = A + (size_t)(bm0 + wave * 16 + srow) * K + scol;
  const bf16* gA1 = A + (size_t)(bm0 + (wave + 4) * 16 + srow) * K + scol;
  const bf16* gB0 = Bw + (size_t)(bn0 + wave * 16 + srow) * K + scol;
  const bf16* gB1 = Bw + (size_t)(bn0 + (wave + 4) * 16 + srow) * K + scol;

  for (int k0 = 0; k0 < K; k0 += 32) {
    gload_lds16(gA0 + k0, &As[wave * 512]);
    gload_lds16(gA1 + k0, &As[(wave + 4) * 512]);
    gload_lds16(gB0 + k0, &Bs[wave * 512]);
    gload_lds16(gB1 + k0, &Bs[(wave + 4) * 512]);
    __syncthreads();
    bf16x8 af[4], bfr[4];
#pragma unroll
    for (int mr = 0; mr < 4; mr++)
      af[mr] = *(const bf16x8*)&As[(wr * 64 + mr * 16 + fr) * 32 + g8];
#pragma unroll
    for (int nr = 0; nr < 4; nr++)
      bfr[nr] = *(const bf16x8*)&Bs[(wc * 64 + nr * 16 + fr) * 32 + g8];
#pragma unroll
    for (int mr = 0; mr < 4; mr++)
#pragma unroll
      for (int nr = 0; nr < 4; nr++)
        acc[mr][nr] = mfma16(af[mr], bfr[nr], acc[mr][nr]);
    __syncthreads();
  }

#pragma unroll
  for (int mr = 0; mr < 4; mr++) {
#pragma unroll
    for (int nr = 0; nr < 4; nr++) {
#pragma unroll
      for (int r = 0; r < 4; r++) {
        const int row = bm0 + wr * 64 + mr * 16 + r4 + r;
        const int col = bn0 + wc * 64 + nr * 16 + fr;
        const float vsum = acc[mr][nr][r];
        if (EPI == 0) {
          ((bf16*)o0)[(size_t)row * N + col] = __float2bfloat16(vsum);
        } else if (EPI == 1) {
          const int sel = col >> 10;
          const int n = col & 1023;
          const int h = n >> 6, d = n & 63;
          const int b = row >> 11, t = row & 2047;
          if (sel == 2) {
            // V transposed: (B,H,D,T)
            ((bf16*)o2)[(((size_t)(b * NHEAD + h)) * DHEAD + d) * T_SEQ + t] =
                __float2bfloat16(vsum);
          } else {
            bf16* dst = (sel == 0) ? (bf16*)o0 : (bf16*)o1;
            dst[(((size_t)(b * NHEAD + h)) * T_SEQ + t) * DHEAD + d] = __float2bfloat16(vsum);
          }
        } else if (EPI == 2) {
          ((float*)o0)[(size_t)row * N + col] = res[(size_t)row * N + col] + vsum;
        } else {  // EPI == 4: fused gate/up + silu
          const float other = __shfl_xor(vsum, 1);
          if ((fr & 1) == 0) {
            const float g = vsum, u = other;
            const float s = g / (1.f + __expf(-g));
            ((bf16*)o0)[(size_t)row * (N >> 1) + (col >> 1)] =
                __float2bfloat16(s * u);
          }
        }
      }
    }
  }
}

// ---------------- causal flash attention, shared LDS staging + heavy key-split
// (r8/r9-verified structure, byte-identical body)
__global__ __launch_bounds__(256) void attn_k(const bf16* __restrict__ qb,
                                              const bf16* __restrict__ kb,
                                              const bf16* __restrict__ vt,
                                              bf16* __restrict__ y,
                                              unsigned short* __restrict__ pO,
                                              float* __restrict__ pL) {
  const int wave = threadIdx.x >> 6, lane = threadIdx.x & 63;
  const int bid = blockIdx.x;
  int bh, qt, ks0, nb, heavy, hs;
  if (bid < 1024) {
    const int c = bid & 7, r = bid >> 3;
    bh = c * 4 + (r & 3);
    const int idx = r >> 2;
    qt = 31 - (idx >> 1);
    hs = idx & 1;
    heavy = 1;
    nb = qt + 1;
    ks0 = hs * nb;
  } else {
    const int bd = bid - 1024;
    const int c = bd & 7, r = bd >> 3;
    bh = c * 4 + (r & 3);
    qt = 15 - (r >> 2);
    hs = 0;
    heavy = 0;
    nb = 2 * qt + 2;
    ks0 = 0;
  }
  const int b = bh >> 4, h = bh & 15;
  const int fr = lane & 15, g8 = (lane >> 4) * 8, r4 = (lane >> 4) * 4;
  const int u = lane >> 4;
  const int src1 = fr + ((u & 1) << 5);
  const int src2 = src1 + 16;
  const bool hB = u >= 2;

  const bf16* qp = qb + (size_t)bh * T_SEQ * DHEAD;
  const bf16* kp = kb + (size_t)bh * T_SEQ * DHEAD;
  const bf16* vp = vt + (size_t)bh * DHEAD * T_SEQ;

  __shared__ char Ks[2][4096];  // 32 rows x 128B, slot-swizzled
  __shared__ char Vs[2][4096];  // 64 rows x 64B,  slot-swizzled

  const int q0 = qt * 64 + wave * 16;
  const int kend = q0 + 16;
  const int qrow = q0 + fr;

  const bf16x8 qf0 = *(const bf16x8*)(qp + (size_t)(q0 + fr) * DHEAD + g8);
  const bf16x8 qf1 = *(const bf16x8*)(qp + (size_t)(q0 + fr) * DHEAD + 32 + g8);

  // staging lane geometry (source pre-swizzled so linear LDS dest = swizzled)
  const int krow_l = lane >> 3;
  const int kslot_l = (lane & 7) ^ krow_l;
  const int vrow_l = lane >> 2;
  const int vslot_l = (lane & 3) ^ ((lane >> 3) & 3);

  // read-side swizzled LDS byte offsets
  const int kswz = (fr & 7) << 4;
  const int koffA = fr * 128 + ((u * 16) ^ kswz);
  const int koffB = fr * 128 + (((4 + u) * 16) ^ kswz);
  const int vswz = ((fr >> 1) & 3) << 4;

  const f32x4 fzero = {0.f, 0.f, 0.f, 0.f};
  f32x4 acc[4];
  float lpart = 0.f;
#pragma unroll
  for (int nf = 0; nf < 4; nf++) acc[nf] = fzero;

  // prologue: stage first tile
  gload_lds16(kp + (size_t)(ks0 * 32 + wave * 8 + krow_l) * DHEAD + kslot_l * 8,
              &Ks[0][wave * 1024]);
  gload_lds16(vp + (size_t)(wave * 16 + vrow_l) * T_SEQ + ks0 * 32 + vslot_l * 8,
              &Vs[0][wave * 1024]);
  __syncthreads();

  for (int ts = 0; ts < nb; ++ts) {
    const int kt = (ks0 + ts) * 32;
    const int buf = ts & 1;
    if (ts + 1 < nb) {  // block-uniform
      const int kn = kt + 32;
      gload_lds16(kp + (size_t)(kn + wave * 8 + krow_l) * DHEAD + kslot_l * 8,
                  &Ks[buf ^ 1][wave * 1024]);
      gload_lds16(vp + (size_t)(wave * 16 + vrow_l) * T_SEQ + kn + vslot_l * 8,
                  &Vs[buf ^ 1][wave * 1024]);
    }
    if (kt < kend) {  // wave-uniform causal skip
      const char* KB = Ks[buf];
      const char* VB = Vs[buf];
      const bf16x8 kf0a = *(const bf16x8*)(KB + koffA);
      const bf16x8 kf0b = *(const bf16x8*)(KB + koffB);
      const bf16x8 kf1a = *(const bf16x8*)(KB + 2048 + koffA);
      const bf16x8 kf1b = *(const bf16x8*)(KB + 2048 + koffB);
      bf16x8 vf[4];
#pragma unroll
      for (int nf = 0; nf < 4; nf++)
        vf[nf] = *(const bf16x8*)(VB + (nf * 16 + fr) * 64 + ((u * 16) ^ vswz));

      // swapped QK^T: S^T[k][q]; lane: q = fr, k_local = r4 + r (+16 for s1)
      f32x4 s0 = mfma16(kf0a, qf0, fzero);
      s0 = mfma16(kf0b, qf1, s0);
      f32x4 s1 = mfma16(kf1a, qf0, fzero);
      s1 = mfma16(kf1b, qf1, s1);

      float x0[4], x1[4];
      if (kt + 31 < q0) {  // fully below diagonal: no causal mask needed
#pragma unroll
        for (int r = 0; r < 4; r++) {
          x0[r] = __expf(fminf(s0[r] * 0.125f, 30.f));
          x1[r] = __expf(fminf(s1[r] * 0.125f, 30.f));
          lpart += x0[r] + x1[r];
        }
      } else {
#pragma unroll
        for (int r = 0; r < 4; r++) {
          const int k0 = kt + r4 + r;
          const int k1 = k0 + 16;
          x0[r] = (k0 <= qrow) ? __expf(fminf(s0[r] * 0.125f, 30.f)) : 0.f;
          x1[r] = (k1 <= qrow) ? __expf(fminf(s1[r] * 0.125f, 30.f)) : 0.f;
          lpart += x0[r] + x1[r];
        }
      }

      // pack P^T values (bf16 pairs along k)
      const int A01 = (int)((unsigned)f2bu(x0[0]) | ((unsigned)f2bu(x0[1]) << 16));
      const int A23 = (int)((unsigned)f2bu(x0[2]) | ((unsigned)f2bu(x0[3]) << 16));
      const int B01 = (int)((unsigned)f2bu(x1[0]) | ((unsigned)f2bu(x1[1]) << 16));
      const int B23 = (int)((unsigned)f2bu(x1[2]) | ((unsigned)f2bu(x1[3]) << 16));

      // rebuild B-frag P^T: dest lane (fr, u) needs k = 8*u .. 8*u+7
      const int t0a = __shfl(A01, src1), t0b = __shfl(B01, src1);
      const int t1a = __shfl(A23, src1), t1b = __shfl(B23, src1);
      const int t2a = __shfl(A01, src2), t2b = __shfl(B01, src2);
      const int t3a = __shfl(A23, src2), t3b = __shfl(B23, src2);
      i32x4 pw;
      pw[0] = hB ? t0b : t0a;
      pw[1] = hB ? t1b : t1a;
      pw[2] = hB ? t2b : t2a;
      pw[3] = hB ? t3b : t3a;
      const bf16x8 pb = __builtin_bit_cast(bf16x8, pw);

      // PV: O^T (partial) = V^T * P^T
#pragma unroll
      for (int nf = 0; nf < 4; nf++) acc[nf] = mfma16(vf[nf], pb, acc[nf]);
    }
    __syncthreads();  // stage(ts+1) done; reads of buf done before overwrite
  }

  // per-row k-subset combine across the 4 lanes sharing fr
  lpart += __shfl_xor(lpart, 16);
  lpart += __shfl_xor(lpart, 32);

  if (!heavy) {
    const float inv = 1.f / lpart;
    const int t = q0 + fr;
    unsigned short* yb =
        (unsigned short*)(y + (((size_t)(b * T_SEQ + t)) * NHEAD + h) * DHEAD);
#pragma unroll
    for (int nf = 0; nf < 4; nf++) {
      ushort4 ov;
      ov.x = f2bu(acc[nf][0] * inv);
      ov.y = f2bu(acc[nf][1] * inv);
      ov.z = f2bu(acc[nf][2] * inv);
      ov.w = f2bu(acc[nf][3] * inv);
      *(ushort4*)(yb + nf * 16 + r4) = ov;
    }
  } else {
    // raw partials to slot hs (rows 1024..2047 -> local 0..1023)
    const int tl = q0 - 1024 + fr;
    unsigned short* po = pO + ((size_t)(hs * 32 + bh) * 1024 + tl) * DHEAD;
#pragma unroll
    for (int nf = 0; nf < 4; nf++) {
      ushort4 ov;
      ov.x = f2bu(acc[nf][0]);
      ov.y = f2bu(acc[nf][1]);
      ov.z = f2bu(acc[nf][2]);
      ov.w = f2bu(acc[nf][3]);
      *(ushort4*)(po + nf * 16 + r4) = ov;
    }
    if (lane < 16) pL[(size_t)(hs * 32 + bh) * 1024 + (q0 - 1024) + lane] = lpart;
  }
}

// ---------------- combine heavy partials -> Y rows 1024..2047 ----------------
__global__ __launch_bounds__(256) void comb_k(const unsigned short* __restrict__ pO,
                                              const float* __restrict__ pL,
                                              bf16* __restrict__ y) {
  const int idx = blockIdx.x * 256 + threadIdx.x;  // 16 threads per row
  const int row = idx >> 4;                        // bh*1024 + tl
  const int d0 = (idx & 15) * 4;
  const int bh = row >> 10, tl = row & 1023;
  const int b = bh >> 4, h = bh & 15;
  const int t = 1024 + tl;
  const float inv = 1.f / (pL[row] + pL[32768 + row]);
  const ushort4 a = *(const ushort4*)(pO + (size_t)row * DHEAD + d0);
  const ushort4 c = *(const ushort4*)(pO + (size_t)(32768 + row) * DHEAD + d0);
  ushort4 ov;
  ov.x = f2bu((b2f(a.x) + b2f(c.x)) * inv);
  ov.y = f2bu((b2f(a.y) + b2f(c.y)) * inv);
  ov.z = f2bu((b2f(a.z) + b2f(c.z)) * inv);
  ov.w = f2bu((b2f(a.w) + b2f(c.w)) * inv);
  *(ushort4*)((unsigned short*)y + (((size_t)(b * T_SEQ + t)) * NHEAD + h) * DHEAD + d0) = ov;
}

// ---------------- launch ----------------
extern "C" void kernel_launch(void* const* d_in, const int* in_sizes, int n_in,
                              void* d_out, int out_size, void* d_ws, size_t ws_size,
                              hipStream_t stream) {
  const float* x     = (const float*)d_in[0];
  const float* ln1w  = (const float*)d_in[1];
  const float* ln2w  = (const float*)d_in[2];
  const float* qkvw  = (const float*)d_in[3];
  const float* ow    = (const float*)d_in[4];
  const float* gatew = (const float*)d_in[5];
  const float* upw   = (const float*)d_in[6];
  const float* downw = (const float*)d_in[7];

  uint8_t* ws = (uint8_t*)d_ws;
  // workspace layout (bytes); ~80 MB total with aliasing
  bf16* WQKV = (bf16*)(ws + 0);          // 6291456
  bf16* WO   = (bf16*)(ws + 6291456);    // 2097152
  bf16* WGU  = (bf16*)(ws + 8388608);    // 8388608  (4096 x 1024, rows interleaved g/u)
  bf16* WD   = (bf16*)(ws + 16777216);   // 4194304
  bf16* H    = (bf16*)(ws + 20971520);   // 8388608
  bf16* Q    = (bf16*)(ws + 29360128);   // 8388608
  bf16* Kb   = (bf16*)(ws + 37748736);   // 8388608
  bf16* VT   = (bf16*)(ws + 46137344);   // 8388608  (B,H,64,T)
  bf16* Y    = (bf16*)(ws + 54525952);   // 8388608
  float* X2  = (float*)(ws + 62914560);  // 16777216 -> end 79691776
  // FFN phase aliases (Q/Kb/VT/Y dead after o-proj):
  bf16* G = (bf16*)(ws + 29360128);      // 16777216 (4096 x 2048) = silu(g)*u
  // attn-phase aliases (dead regions during attention):
  unsigned short* pO = (unsigned short*)(ws + 62914560);  // 8MB partials (X2 region)
  float* pL = (float*)(ws + 20971520);                    // 256KB lsums (H region)

  // weights -> bf16 (single dispatch; gate/up interleaved into WGU)
  f2ball_k<<<10240, 256, 0, stream>>>(qkvw, ow, gatew, upw, downw, (bf16*)ws);

  // attn path
  rms_k<<<MROWS, 256, 0, stream>>>(x, ln1w, H);
  gemm_bt<1024, 1><<<dim3(24, 32), 256, 0, stream>>>(H, WQKV, 3072, Q, Kb, VT, nullptr);
  attn_k<<<1536, 256, 0, stream>>>(Q, Kb, VT, Y, pO, pL);
  comb_k<<<2048, 256, 0, stream>>>(pO, pL, Y);
  gemm_bt<1024, 2><<<dim3(8, 32), 256, 0, stream>>>(Y, WO, 1024, X2, nullptr, nullptr, x);

  // ffn path: fused gate+up GEMM with silu epilogue -> G, then down GEMM
  rms_k<<<MROWS, 256, 0, stream>>>(X2, ln2w, H);
  gemm_bt<1024, 4><<<dim3(32, 32), 256, 0, stream>>>(H, WGU, 4096, G, nullptr, nullptr, nullptr);
  gemm_bt<2048, 2><<<dim3(8, 32), 256, 0, stream>>>(G, WD, 1024, (float*)d_out, nullptr, nullptr, X2);
}